// Round 8
// baseline (1588.887 us; speedup 1.0000x reference)
//
#include <hip/hip_runtime.h>
#include <hip/hip_bf16.h>
#include <stdint.h>

// ---------------- problem constants ----------------
#define NTOK   8192
#define DMODEL 2048
#define FFN    2048
#define NEXP   16
#define TOPK   4
#define STRIDE (NTOK + 256)                 // per-expert ids stride

#define BM 256
#define BK 64
#define NKT 32                              // K-tiles (K=2048 / 64)
#define NIT 16                              // 2 K-tiles per iteration
#define MAXT ((NTOK*TOPK)/BM + NEXP)        // 144 worst-case M-tiles

typedef __attribute__((ext_vector_type(4))) float    f32x4;
typedef __attribute__((ext_vector_type(4))) _Float16 f16x4;
typedef __attribute__((ext_vector_type(8))) _Float16 f16x8;

typedef __attribute__((address_space(1))) void gvoid;
typedef __attribute__((address_space(3))) void lvoid;
#define GLDS16(gp, lp) __builtin_amdgcn_global_load_lds((gvoid*)(gp), (lvoid*)(lp), 16, 0, 0)

#define MFMA16(a,b,c) __builtin_amdgcn_mfma_f32_16x16x32_f16((a),(b),(c),0,0,0)
#define BAR __builtin_amdgcn_s_barrier()
#define LGK asm volatile("s_waitcnt lgkmcnt(0)" ::: "memory")
#define VMW2 asm volatile("s_waitcnt vmcnt(2)" ::: "memory")
#define VMW0 asm volatile("s_waitcnt vmcnt(0)" ::: "memory")

// ---------------- prep kernels ----------------

__global__ void k_sentinel(float* o){ o[0] = 3.0e7f; }   // ws too small marker

// transpose 2048x2048 fp32 -> fp16 (dst[c][r] = src[r][c]); z/16 selects matrix.
__global__ __launch_bounds__(256) void k_transpose3(const float* __restrict__ s0,
                                                    const float* __restrict__ s1,
                                                    const float* __restrict__ s2,
                                                    _Float16* __restrict__ d0,
                                                    _Float16* __restrict__ d1,
                                                    _Float16* __restrict__ d2){
  __shared__ float lds[64][65];
  int z = blockIdx.z;
  const float* S; _Float16* D;
  if (z < 16)      { S = s0 + (size_t)z * DMODEL * FFN;      D = d0 + (size_t)z * DMODEL * FFN; }
  else if (z < 32) { S = s1 + (size_t)(z-16) * DMODEL * FFN; D = d1 + (size_t)(z-16) * DMODEL * FFN; }
  else             { S = s2 + (size_t)(z-32) * DMODEL * FFN; D = d2 + (size_t)(z-32) * DMODEL * FFN; }
  const int tid = threadIdx.x;
  const int x0 = blockIdx.x * 64, y0 = blockIdx.y * 64;
  {
    int row = tid >> 2, cq = (tid & 3) * 16;
    const float* srow = S + (size_t)(y0 + row) * 2048 + x0 + cq;
#pragma unroll
    for (int k = 0; k < 4; ++k){
      float4 v = *(const float4*)(srow + 4*k);
      lds[row][cq + 4*k + 0] = v.x; lds[row][cq + 4*k + 1] = v.y;
      lds[row][cq + 4*k + 2] = v.z; lds[row][cq + 4*k + 3] = v.w;
    }
  }
  __syncthreads();
#pragma unroll
  for (int jj = 0; jj < 2; ++jj){
    int slot = tid + 256*jj;
    int c = slot >> 3, ch = slot & 7;
    f16x8 h;
#pragma unroll
    for (int i = 0; i < 8; ++i) h[i] = (_Float16)lds[ch*8 + i][c];
    *(f16x8*)(D + (size_t)(x0 + c) * 2048 + y0 + ch*8) = h;
  }
}

// ---------------- router (fused with x -> fp16 convert), 1 token/wave ----------------
__global__ __launch_bounds__(256) void k_router(const float* __restrict__ x,
                                                const float* __restrict__ wr,
                                                int*   __restrict__ counts,
                                                int*   __restrict__ ids,
                                                int*   __restrict__ slotmap,
                                                float* __restrict__ wk,
                                                _Float16* __restrict__ xh){
  const int wv = threadIdx.x >> 6, lane = threadIdx.x & 63;
  const int t = blockIdx.x * 4 + wv;
  const float4* x4 = (const float4*)(x + (size_t)t * DMODEL);
  const float4* w4 = (const float4*)wr;
  float acc[NEXP];
#pragma unroll
  for (int e = 0; e < NEXP; ++e) acc[e] = 0.f;
#pragma unroll
  for (int i = 0; i < 8; ++i){
    int d4 = lane + i*64;
    float4 xv = x4[d4];
    f16x4 h; h[0]=(_Float16)xv.x; h[1]=(_Float16)xv.y; h[2]=(_Float16)xv.z; h[3]=(_Float16)xv.w;
    *(f16x4*)(xh + (size_t)t*DMODEL + d4*4) = h;
#pragma unroll
    for (int e = 0; e < NEXP; ++e){
      float4 wv_ = w4[e*512 + d4];
      acc[e] += xv.x*wv_.x + xv.y*wv_.y + xv.z*wv_.z + xv.w*wv_.w;
    }
  }
#pragma unroll
  for (int e = 0; e < NEXP; ++e){
    float v = acc[e];
#pragma unroll
    for (int s = 32; s > 0; s >>= 1) v += __shfl_xor(v, s);
    acc[e] = v;
  }
  if (lane == 0){
    int mask = 0; float tv[TOPK]; int te[TOPK];
    for (int k = 0; k < TOPK; ++k){      // strict '>' keeps lowest index on ties
      float best = -3.0e38f; int bi = 0;
      for (int e = 0; e < NEXP; ++e)
        if (!((mask >> e) & 1) && acc[e] > best){ best = acc[e]; bi = e; }
      mask |= 1 << bi; tv[k] = best; te[k] = bi;
    }
    float m = tv[0], s = 0.f, w[TOPK];
    for (int k = 0; k < TOPK; ++k){ w[k] = __expf(tv[k] - m); s += w[k]; }
    float inv = 1.f / s;
    for (int k = 0; k < TOPK; ++k){
      int slot = atomicAdd(&counts[te[k]], 1);
      ids[te[k]*STRIDE + slot] = t;
      slotmap[t*TOPK + k] = (te[k] << 16) | slot;
      wk[t*TOPK + k] = w[k] * inv;
    }
  }
}

// =========== shared 8-phase GEMM machinery (macros over kernel locals) ===========
#define RD_B(q,kx) { _Pragma("unroll") for (int n = 0; n < 4; ++n) \
    bf[n] = *(const f16x8*)(Bb + (q)*32768 + (bB[n] ^ (kx))); }
#define RD_A(q,kx,mh) { _Pragma("unroll") for (int m = 0; m < 4; ++m) \
    af[m] = *(const f16x8*)(Ab + (q)*32768 + (aB[(mh)*4+m] ^ (kx))); }
#define MM(mh) { __builtin_amdgcn_s_setprio(1); \
    _Pragma("unroll") for (int m = 0; m < 4; ++m) \
    _Pragma("unroll") for (int n = 0; n < 4; ++n) \
      acc[(mh)*4+m][n] = MFMA16(bf[n], af[m], acc[(mh)*4+m][n]); \
    __builtin_amdgcn_s_setprio(0); }
#define STG_A(T,h) { _Pragma("unroll") for (int j = 0; j < 2; ++j) \
    GLDS16(srcA[h][j] + (size_t)(T)*128, ldsA + ((T)&1)*32768 + (h)*16384 + j*8192 + wdst); }
#define STG_B(T,h) { _Pragma("unroll") for (int j = 0; j < 2; ++j) \
    GLDS16(srcB[h][j] + (size_t)(T)*128, ldsB + ((T)&1)*32768 + (h)*16384 + j*8192 + wdst); }
#define ITER8(t1,t2,t3,F) \
  RD_B(0,0);  RD_A(0,0,0);  STG_B(t1,1);            BAR; LGK; MM(0); BAR; \
  RD_A(0,0,1);              STG_A(t1,0);            BAR; LGK; MM(1); BAR; \
  RD_B(0,64); RD_A(0,64,0); STG_A(t1,1);            BAR; LGK; MM(0); BAR; \
  RD_A(0,64,1);             if (F){ STG_B(t2,0); }  BAR; LGK; MM(1); \
  if (F){ VMW2; } else { VMW0; }                    BAR; \
  RD_B(1,0);  RD_A(1,0,0);  if (F){ STG_B(t2,1); }  BAR; LGK; MM(0); BAR; \
  RD_A(1,0,1);              if (F){ STG_A(t2,0); }  BAR; LGK; MM(1); BAR; \
  RD_B(1,64); RD_A(1,64,0); if (F){ STG_A(t2,1); }  BAR; LGK; MM(0); BAR; \
  RD_A(1,64,1);             if (F){ STG_B(t3,0); }  BAR; LGK; MM(1); \
  if (F){ VMW2; }                                   BAR;

// ================= grouped GEMM 1: H = silu(X@Wg)*(X@Wu) =================
// N-split: dispatch covers 8 of 16 N-col-groups, nbase = 0 or 8 (half-grids of
// MAXT*8 blocks each so k_down surfaces in the profiler top-5).
__global__ __launch_bounds__(512, 2) void k_gateup(
    const _Float16* __restrict__ xh,
    const _Float16* __restrict__ wgT,   // [E][F][D]
    const _Float16* __restrict__ wuT,
    const int* __restrict__ counts,
    const int* __restrict__ ids,
    _Float16* __restrict__ H,
    int nbase)
{
  __shared__ __align__(128) char smem[131072];
  char* ldsA = smem;
  char* ldsB = smem + 65536;

  // XCD-bijective chunking + 4-N-column grouping (r6 mapping, grid = MAXT*8)
  const int bid = blockIdx.x;
  const int vid = (bid & 7) * MAXT + (bid >> 3);
  const int g = vid / (4*MAXT), rem = vid % (4*MAXT);
  const int mt_lin = rem >> 2;
  const int n0 = (nbase + g*4 + (rem & 3)) * 128;

  int e = -1, mt = 0, rowbase = 0;
  { int at = 0, rb = 0;
    for (int i = 0; i < NEXP; ++i){
      int c = counts[i]; int nt = (c + 255) >> 8;
      if (e < 0 && mt_lin < at + nt){ e = i; mt = mt_lin - at; rowbase = rb; }
      at += nt; rb += nt * BM;
    } }
  if (e < 0) return;

  const int tid = threadIdx.x, lane = tid & 63, w = tid >> 6;
  const int wm = w >> 2, wn = w & 3, hi = lane >> 4, l15 = lane & 15;
  const int wdst = w * 1024;

  const int chunk = (((tid & 7) ^ ((tid >> 3) & 7)) << 4);
  const char* srcA[2][2]; const char* srcB[2][2];
#pragma unroll
  for (int h = 0; h < 2; ++h)
#pragma unroll
    for (int j = 0; j < 2; ++j){
      int r = h*128 + j*64 + (tid >> 3);
      int tok = ids[e*STRIDE + mt*BM + r];
      srcA[h][j] = (const char*)(xh + (size_t)tok * DMODEL) + chunk;
      int which = (r >> 5) & 1, col = n0 + ((r >> 6) << 5) + (r & 31);
      const _Float16* Wm = which ? wuT : wgT;
      srcB[h][j] = (const char*)(Wm + ((size_t)e * FFN + col) * (size_t)DMODEL) + chunk;
    }

  const char* Ab = ldsA + wm*16384;
  const char* Bb = ldsB + (wn >> 1)*16384 + (wn & 1)*8192;
  const int sl0 = (hi ^ (l15 & 7)) << 4;
  int aB[8], bB[4];
#pragma unroll
  for (int m = 0; m < 8; ++m) aB[m] = m*2048 + l15*128 + sl0;
#pragma unroll
  for (int n = 0; n < 4; ++n) bB[n] = n*2048 + l15*128 + sl0;

  f32x4 acc[8][4];
#pragma unroll
  for (int m = 0; m < 8; ++m)
#pragma unroll
    for (int n = 0; n < 4; ++n) acc[m][n] = (f32x4)(0.0f);

  STG_B(0,0); STG_B(0,1); STG_A(0,0); STG_A(0,1); STG_B(1,0);
  VMW2; BAR;

  f16x8 af[4], bf[4];
  for (int i = 0; i < NIT-1; ++i){
    ITER8(2*i+1, 2*i+2, 2*i+3, 1)
  }
  ITER8(31, 32, 33, 0)

  const int hrow0 = rowbase + mt*BM + wm*128;
#pragma unroll
  for (int m = 0; m < 8; ++m){
    int row = hrow0 + m*16 + l15;
#pragma unroll
    for (int nf = 0; nf < 2; ++nf){
      f16x4 hv;
#pragma unroll
      for (int j = 0; j < 4; ++j){
        float gv = acc[m][nf][j], uv = acc[m][nf+2][j];
        hv[j] = (_Float16)(gv / (1.f + __expf(-gv)) * uv);
      }
      *(f16x4*)(H + (size_t)row * FFN + n0 + wn*32 + nf*16 + hi*4) = hv;
    }
  }
}

// ================= grouped GEMM 2: Y = H @ Wd (plain stores, split Y) =================
__global__ __launch_bounds__(512, 2) void k_down(
    const _Float16* __restrict__ H,
    const _Float16* __restrict__ wdT,   // [E][D][F]
    const int* __restrict__ counts,
    _Float16* __restrict__ Yw2,         // rows < 32768  (dead wuT region)
    _Float16* __restrict__ Yxh)         // rows >= 32768 (dead xh region)
{
  __shared__ __align__(128) char smem[131072];
  char* ldsA = smem;
  char* ldsB = smem + 65536;

  // r6 mapping: XCD chunking + 4-N-column grouping (grid = MAXT*8)
  const int bid = blockIdx.x;
  const int vid = (bid & 7) * MAXT + (bid >> 3);
  const int g = vid / (4*MAXT), rem = vid % (4*MAXT);
  const int mt_lin = rem >> 2;
  const int n0 = (g*4 + (rem & 3)) * 256;

  int e = -1, mt = 0, rowbase = 0;
  { int at = 0, rb = 0;
    for (int i = 0; i < NEXP; ++i){
      int c = counts[i]; int nt = (c + 255) >> 8;
      if (e < 0 && mt_lin < at + nt){ e = i; mt = mt_lin - at; rowbase = rb; }
      at += nt; rb += nt * BM;
    } }
  if (e < 0) return;

  const int tid = threadIdx.x, lane = tid & 63, w = tid >> 6;
  const int wm = w >> 2, wn = w & 3, hi = lane >> 4, l15 = lane & 15;
  const int wdst = w * 1024;

  const int chunk = (((tid & 7) ^ ((tid >> 3) & 7)) << 4);
  const char* srcA[2][2]; const char* srcB[2][2];
#pragma unroll
  for (int h = 0; h < 2; ++h)
#pragma unroll
    for (int j = 0; j < 2; ++j){
      int r = h*128 + j*64 + (tid >> 3);
      srcA[h][j] = (const char*)(H + (size_t)(rowbase + mt*BM + r) * FFN) + chunk;
      srcB[h][j] = (const char*)(wdT + ((size_t)e * DMODEL + n0 + r) * (size_t)FFN) + chunk;
    }

  const char* Ab = ldsA + wm*16384;
  const char* Bb = ldsB + (wn >> 1)*16384 + (wn & 1)*8192;
  const int sl0 = (hi ^ (l15 & 7)) << 4;
  int aB[8], bB[4];
#pragma unroll
  for (int m = 0; m < 8; ++m) aB[m] = m*2048 + l15*128 + sl0;
#pragma unroll
  for (int n = 0; n < 4; ++n) bB[n] = n*2048 + l15*128 + sl0;

  f32x4 acc[8][4];
#pragma unroll
  for (int m = 0; m < 8; ++m)
#pragma unroll
    for (int n = 0; n < 4; ++n) acc[m][n] = (f32x4)(0.0f);

  STG_B(0,0); STG_B(0,1); STG_A(0,0); STG_A(0,1); STG_B(1,0);
  VMW2; BAR;

  f16x8 af[4], bf[4];
  for (int i = 0; i < NIT-1; ++i){
    ITER8(2*i+1, 2*i+2, 2*i+3, 1)
  }
  ITER8(31, 32, 33, 0)

  const int row0 = rowbase + mt*BM + wm*128;
#pragma unroll
  for (int m = 0; m < 8; ++m){
    int row = row0 + m*16 + l15;
    _Float16* yb = (row < 32768) ? (Yw2 + (size_t)row * DMODEL)
                                 : (Yxh + (size_t)(row - 32768) * DMODEL);
#pragma unroll
    for (int n = 0; n < 4; ++n){
      f16x4 yv;
#pragma unroll
      for (int j = 0; j < 4; ++j) yv[j] = (_Float16)acc[m][n][j];
      *(f16x4*)(yb + n0 + wn*64 + n*16 + hi*4) = yv;
    }
  }
}

// ---------------- combine: out[t] = sum_k wk * Y[slot_k] ----------------
__global__ __launch_bounds__(256) void k_combine(const _Float16* __restrict__ Yw2,
                                                 const _Float16* __restrict__ Yxh,
                                                 const int* __restrict__ counts,
                                                 const int* __restrict__ slotmap,
                                                 const float* __restrict__ wk,
                                                 float* __restrict__ out){
  __shared__ int pre[NEXP];
  const int t = blockIdx.x, c = threadIdx.x;
  if (c == 0){
    int a = 0;
    for (int i = 0; i < NEXP; ++i){ pre[i] = a; a += ((counts[i] + 255) >> 8) << 8; }
  }
  __syncthreads();
  float o[8];
#pragma unroll
  for (int i = 0; i < 8; ++i) o[i] = 0.f;
#pragma unroll
  for (int k = 0; k < TOPK; ++k){
    int sm = slotmap[t*TOPK + k];
    int row = pre[sm >> 16] + (sm & 0xffff);
    float wv = wk[t*TOPK + k];
    const _Float16* yb = (row < 32768) ? (Yw2 + (size_t)row * DMODEL)
                                       : (Yxh + (size_t)(row - 32768) * DMODEL);
    f16x8 y = *(const f16x8*)(yb + c*8);
#pragma unroll
    for (int i = 0; i < 8; ++i) o[i] += wv * (float)y[i];
  }
  float4 lo = {o[0], o[1], o[2], o[3]}, hu = {o[4], o[5], o[6], o[7]};
  float* op = out + (size_t)t * DMODEL + c*8;
  *(float4*)op = lo;
  *(float4*)(op + 4) = hu;
}

// ---------------- host launch ----------------
extern "C" void kernel_launch(void* const* d_in, const int* in_sizes, int n_in,
                              void* d_out, int out_size, void* d_ws, size_t ws_size,
                              hipStream_t stream)
{
  const float* x  = (const float*)d_in[0];
  const float* wr = (const float*)d_in[1];
  const float* wg = (const float*)d_in[2];
  const float* wu = (const float*)d_in[3];
  const float* wd = (const float*)d_in[4];
  float* out = (float*)d_out;
  char* ws = (char*)d_ws;

  // layout (NEED ~588 MB <= proven-available 605 MB, from r3/r4 useY equality):
  // [counts | ids | slotmap | wk | xh(32M) | W1(134M) | H(151M) | W2(134M) | WD(134M)]
  // Y: rows<32768 -> W2 (wuT dead after gateup), rest -> xh (dead after gateup).
  const size_t OFF_IDS  = 256;
  const size_t OFF_SLOT = OFF_IDS  + (size_t)NEXP*STRIDE*4;
  const size_t OFF_WK   = OFF_SLOT + (size_t)NTOK*TOPK*4;
  const size_t OFF_XH   = OFF_WK   + (size_t)NTOK*TOPK*4;
  const size_t OFF_W1   = OFF_XH   + (size_t)NTOK*DMODEL*2;
  const size_t OFF_H    = OFF_W1   + (size_t)NEXP*DMODEL*FFN*2;
  const size_t OFF_W2   = OFF_H    + (size_t)MAXT*BM*FFN*2;
  const size_t OFF_WD   = OFF_W2   + (size_t)NEXP*DMODEL*FFN*2;
  const size_t NEED     = OFF_WD   + (size_t)NEXP*DMODEL*FFN*2;
  if (ws_size < NEED){ k_sentinel<<<1,1,0,stream>>>(out); return; }

  int*      counts  = (int*)ws;
  int*      ids     = (int*)(ws + OFF_IDS);
  int*      slotmap = (int*)(ws + OFF_SLOT);
  float*    wk      = (float*)(ws + OFF_WK);
  _Float16* xh      = (_Float16*)(ws + OFF_XH);
  _Float16* wgT     = (_Float16*)(ws + OFF_W1);
  _Float16* wuT     = (_Float16*)(ws + OFF_W2);
  _Float16* wdT     = (_Float16*)(ws + OFF_WD);   // own region: transpose fuses pre-gateup
  _Float16* H       = (_Float16*)(ws + OFF_H);
  _Float16* Yw2     = (_Float16*)(ws + OFF_W2);   // alias wuT (dead after gateup)
  _Float16* Yxh     = (_Float16*)(ws + OFF_XH);   // alias xh  (dead after gateup)

  hipMemsetAsync(ws, 0, OFF_SLOT, stream);    // counts + ids

  k_router<<<NTOK/4, 256, 0, stream>>>(x, wr, counts, ids, slotmap, wk, xh);
  k_transpose3<<<dim3(32,32,48), 256, 0, stream>>>(wg, wu, wd, wgT, wuT, wdT);
  k_gateup<<<MAXT*8, 512, 0, stream>>>(xh, wgT, wuT, counts, ids, H, 0);
  k_gateup<<<MAXT*8, 512, 0, stream>>>(xh, wgT, wuT, counts, ids, H, 8);
  k_down<<<MAXT*8, 512, 0, stream>>>(H, wdT, counts, Yw2, Yxh);
  k_combine<<<NTOK, 256, 0, stream>>>(Yw2, Yxh, counts, slotmap, wk, out);
}

// Round 9
// 1178.345 us; speedup vs baseline: 1.3484x; 1.3484x over previous
//
#include <hip/hip_runtime.h>
#include <hip/hip_bf16.h>
#include <stdint.h>

// ---------------- problem constants ----------------
#define NTOK   8192
#define DMODEL 2048
#define FFN    2048
#define NEXP   16
#define TOPK   4
#define STRIDE (NTOK + 256)                 // per-expert ids stride

#define BM 256
#define BK 64
#define NKT 32                              // K-tiles (K=2048 / 64)
#define NIT 16                              // 2 K-tiles per iteration
#define MAXT ((NTOK*TOPK)/BM + NEXP)        // 144 worst-case M-tiles
#define RTB 32                              // tokens per router block

typedef __attribute__((ext_vector_type(4))) float    f32x4;
typedef __attribute__((ext_vector_type(4))) _Float16 f16x4;
typedef __attribute__((ext_vector_type(8))) _Float16 f16x8;

typedef __attribute__((address_space(1))) void gvoid;
typedef __attribute__((address_space(3))) void lvoid;
#define GLDS16(gp, lp) __builtin_amdgcn_global_load_lds((gvoid*)(gp), (lvoid*)(lp), 16, 0, 0)

#define MFMA16(a,b,c) __builtin_amdgcn_mfma_f32_16x16x32_f16((a),(b),(c),0,0,0)
#define BAR __builtin_amdgcn_s_barrier()
#define LGK asm volatile("s_waitcnt lgkmcnt(0)" ::: "memory")
#define VMW2 asm volatile("s_waitcnt vmcnt(2)" ::: "memory")
#define VMW0 asm volatile("s_waitcnt vmcnt(0)" ::: "memory")

// ---------------- prep kernels ----------------

__global__ void k_sentinel(float* o){ o[0] = 3.0e7f; }   // ws too small marker

// transpose 2048x2048 fp32 -> fp16 (dst[c][r] = src[r][c]); z/16 selects matrix.
__global__ __launch_bounds__(256) void k_transpose3(const float* __restrict__ s0,
                                                    const float* __restrict__ s1,
                                                    const float* __restrict__ s2,
                                                    _Float16* __restrict__ d0,
                                                    _Float16* __restrict__ d1,
                                                    _Float16* __restrict__ d2){
  __shared__ float lds[64][65];
  int z = blockIdx.z;
  const float* S; _Float16* D;
  if (z < 16)      { S = s0 + (size_t)z * DMODEL * FFN;      D = d0 + (size_t)z * DMODEL * FFN; }
  else if (z < 32) { S = s1 + (size_t)(z-16) * DMODEL * FFN; D = d1 + (size_t)(z-16) * DMODEL * FFN; }
  else             { S = s2 + (size_t)(z-32) * DMODEL * FFN; D = d2 + (size_t)(z-32) * DMODEL * FFN; }
  const int tid = threadIdx.x;
  const int x0 = blockIdx.x * 64, y0 = blockIdx.y * 64;
  {
    int row = tid >> 2, cq = (tid & 3) * 16;
    const float* srow = S + (size_t)(y0 + row) * 2048 + x0 + cq;
#pragma unroll
    for (int k = 0; k < 4; ++k){
      float4 v = *(const float4*)(srow + 4*k);
      lds[row][cq + 4*k + 0] = v.x; lds[row][cq + 4*k + 1] = v.y;
      lds[row][cq + 4*k + 2] = v.z; lds[row][cq + 4*k + 3] = v.w;
    }
  }
  __syncthreads();
#pragma unroll
  for (int jj = 0; jj < 2; ++jj){
    int slot = tid + 256*jj;
    int c = slot >> 3, ch = slot & 7;
    f16x8 h;
#pragma unroll
    for (int i = 0; i < 8; ++i) h[i] = (_Float16)lds[ch*8 + i][c];
    *(f16x8*)(D + (size_t)(x0 + c) * 2048 + y0 + ch*8) = h;
  }
}

// ---------------- router: hierarchical slot assignment (no same-address atomic chains) ----
// 256 blocks x 256 threads; block owns RTB=32 tokens (wave wv: tokens wv*8..wv*8+7).
// Per-token logits/top4 as before; then LDS histogram -> ONE global atomicAdd per
// expert per block (chain 256 instead of 2048x4) -> LDS-offset scatter.
__global__ __launch_bounds__(256) void k_router(const float* __restrict__ x,
                                                const float* __restrict__ wr,
                                                int*   __restrict__ counts,
                                                int*   __restrict__ ids,
                                                int*   __restrict__ slotmap,
                                                float* __restrict__ wk,
                                                _Float16* __restrict__ xh){
  __shared__ unsigned char lte[RTB][TOPK];
  __shared__ int lcnt[NEXP], lbase[NEXP], loff[NEXP];
  const int tid = threadIdx.x, wv = tid >> 6, lane = tid & 63;
  if (tid < NEXP){ lcnt[tid] = 0; loff[tid] = 0; }
  __syncthreads();
  const float4* w4 = (const float4*)wr;
  for (int tt = 0; tt < 8; ++tt){
    const int tl = wv*8 + tt;
    const int t = blockIdx.x * RTB + tl;
    const float4* x4 = (const float4*)(x + (size_t)t * DMODEL);
    float acc[NEXP];
#pragma unroll
    for (int e = 0; e < NEXP; ++e) acc[e] = 0.f;
#pragma unroll
    for (int i = 0; i < 8; ++i){
      int d4 = lane + i*64;
      float4 xv = x4[d4];
      f16x4 h; h[0]=(_Float16)xv.x; h[1]=(_Float16)xv.y; h[2]=(_Float16)xv.z; h[3]=(_Float16)xv.w;
      *(f16x4*)(xh + (size_t)t*DMODEL + d4*4) = h;
#pragma unroll
      for (int e = 0; e < NEXP; ++e){
        float4 wv_ = w4[e*512 + d4];
        acc[e] += xv.x*wv_.x + xv.y*wv_.y + xv.z*wv_.z + xv.w*wv_.w;
      }
    }
#pragma unroll
    for (int e = 0; e < NEXP; ++e){
      float v = acc[e];
#pragma unroll
      for (int s = 32; s > 0; s >>= 1) v += __shfl_xor(v, s);
      acc[e] = v;
    }
    if (lane == 0){
      int mask = 0; float tv[TOPK]; int te[TOPK];
      for (int k = 0; k < TOPK; ++k){    // strict '>' keeps lowest index on ties
        float best = -3.0e38f; int bi = 0;
        for (int e = 0; e < NEXP; ++e)
          if (!((mask >> e) & 1) && acc[e] > best){ best = acc[e]; bi = e; }
        mask |= 1 << bi; tv[k] = best; te[k] = bi;
      }
      float m = tv[0], s = 0.f, w[TOPK];
      for (int k = 0; k < TOPK; ++k){ w[k] = __expf(tv[k] - m); s += w[k]; }
      float inv = 1.f / s;
      for (int k = 0; k < TOPK; ++k){
        lte[tl][k] = (unsigned char)te[k];
        wk[t*TOPK + k] = w[k] * inv;
      }
    }
  }
  __syncthreads();
  if (tid < RTB*TOPK){                       // 128 pairs
    atomicAdd(&lcnt[lte[tid >> 2][tid & 3]], 1);   // LDS atomic
  }
  __syncthreads();
  if (tid < NEXP) lbase[tid] = atomicAdd(&counts[tid], lcnt[tid]);  // 16 global/block
  __syncthreads();
  if (tid < RTB*TOPK){
    int tl = tid >> 2, k = tid & 3;
    int ep = lte[tl][k];
    int slot = lbase[ep] + atomicAdd(&loff[ep], 1);  // LDS atomic
    int t = blockIdx.x * RTB + tl;
    ids[ep*STRIDE + slot] = t;
    slotmap[t*TOPK + k] = (ep << 16) | slot;
  }
}

// =========== shared 8-phase GEMM machinery (macros over kernel locals) ===========
#define RD_B(q,kx) { _Pragma("unroll") for (int n = 0; n < 4; ++n) \
    bf[n] = *(const f16x8*)(Bb + (q)*32768 + (bB[n] ^ (kx))); }
#define RD_A(q,kx,mh) { _Pragma("unroll") for (int m = 0; m < 4; ++m) \
    af[m] = *(const f16x8*)(Ab + (q)*32768 + (aB[(mh)*4+m] ^ (kx))); }
#define MM(mh) { __builtin_amdgcn_s_setprio(1); \
    _Pragma("unroll") for (int m = 0; m < 4; ++m) \
    _Pragma("unroll") for (int n = 0; n < 4; ++n) \
      acc[(mh)*4+m][n] = MFMA16(bf[n], af[m], acc[(mh)*4+m][n]); \
    __builtin_amdgcn_s_setprio(0); }
#define STG_A(T,h) { _Pragma("unroll") for (int j = 0; j < 2; ++j) \
    GLDS16(srcA[h][j] + (size_t)(T)*128, ldsA + ((T)&1)*32768 + (h)*16384 + j*8192 + wdst); }
#define STG_B(T,h) { _Pragma("unroll") for (int j = 0; j < 2; ++j) \
    GLDS16(srcB[h][j] + (size_t)(T)*128, ldsB + ((T)&1)*32768 + (h)*16384 + j*8192 + wdst); }
#define ITER8(t1,t2,t3,F) \
  RD_B(0,0);  RD_A(0,0,0);  STG_B(t1,1);            BAR; LGK; MM(0); BAR; \
  RD_A(0,0,1);              STG_A(t1,0);            BAR; LGK; MM(1); BAR; \
  RD_B(0,64); RD_A(0,64,0); STG_A(t1,1);            BAR; LGK; MM(0); BAR; \
  RD_A(0,64,1);             if (F){ STG_B(t2,0); }  BAR; LGK; MM(1); \
  if (F){ VMW2; } else { VMW0; }                    BAR; \
  RD_B(1,0);  RD_A(1,0,0);  if (F){ STG_B(t2,1); }  BAR; LGK; MM(0); BAR; \
  RD_A(1,0,1);              if (F){ STG_A(t2,0); }  BAR; LGK; MM(1); BAR; \
  RD_B(1,64); RD_A(1,64,0); if (F){ STG_A(t2,1); }  BAR; LGK; MM(0); BAR; \
  RD_A(1,64,1);             if (F){ STG_B(t3,0); }  BAR; LGK; MM(1); \
  if (F){ VMW2; }                                   BAR;

// ================= grouped GEMM 1: H = silu(X@Wg)*(X@Wu) =================
__global__ __launch_bounds__(512, 2) void k_gateup(
    const _Float16* __restrict__ xh,
    const _Float16* __restrict__ wgT,   // [E][F][D]
    const _Float16* __restrict__ wuT,
    const int* __restrict__ counts,
    const int* __restrict__ ids,
    _Float16* __restrict__ H)
{
  __shared__ __align__(128) char smem[131072];
  char* ldsA = smem;
  char* ldsB = smem + 65536;

  // r6 mapping: XCD-bijective chunking + 4-N-column grouping (grid = MAXT*16)
  const int bid = blockIdx.x;
  const int vid = (bid & 7) * (MAXT*2) + (bid >> 3);
  const int g = vid / (4*MAXT), rem = vid % (4*MAXT);
  const int mt_lin = rem >> 2;
  const int n0 = (g*4 + (rem & 3)) * 128;

  int e = -1, mt = 0, rowbase = 0;
  { int at = 0, rb = 0;
    for (int i = 0; i < NEXP; ++i){
      int c = counts[i]; int nt = (c + 255) >> 8;
      if (e < 0 && mt_lin < at + nt){ e = i; mt = mt_lin - at; rowbase = rb; }
      at += nt; rb += nt * BM;
    } }
  if (e < 0) return;

  const int tid = threadIdx.x, lane = tid & 63, w = tid >> 6;
  const int wm = w >> 2, wn = w & 3, hi = lane >> 4, l15 = lane & 15;
  const int wdst = w * 1024;

  const int chunk = (((tid & 7) ^ ((tid >> 3) & 7)) << 4);
  const char* srcA[2][2]; const char* srcB[2][2];
#pragma unroll
  for (int h = 0; h < 2; ++h)
#pragma unroll
    for (int j = 0; j < 2; ++j){
      int r = h*128 + j*64 + (tid >> 3);
      int tok = ids[e*STRIDE + mt*BM + r];
      srcA[h][j] = (const char*)(xh + (size_t)tok * DMODEL) + chunk;
      int which = (r >> 5) & 1, col = n0 + ((r >> 6) << 5) + (r & 31);
      const _Float16* Wm = which ? wuT : wgT;
      srcB[h][j] = (const char*)(Wm + ((size_t)e * FFN + col) * (size_t)DMODEL) + chunk;
    }

  const char* Ab = ldsA + wm*16384;
  const char* Bb = ldsB + (wn >> 1)*16384 + (wn & 1)*8192;
  const int sl0 = (hi ^ (l15 & 7)) << 4;
  int aB[8], bB[4];
#pragma unroll
  for (int m = 0; m < 8; ++m) aB[m] = m*2048 + l15*128 + sl0;
#pragma unroll
  for (int n = 0; n < 4; ++n) bB[n] = n*2048 + l15*128 + sl0;

  f32x4 acc[8][4];
#pragma unroll
  for (int m = 0; m < 8; ++m)
#pragma unroll
    for (int n = 0; n < 4; ++n) acc[m][n] = (f32x4)(0.0f);

  STG_B(0,0); STG_B(0,1); STG_A(0,0); STG_A(0,1); STG_B(1,0);
  VMW2; BAR;

  f16x8 af[4], bf[4];
  for (int i = 0; i < NIT-1; ++i){
    ITER8(2*i+1, 2*i+2, 2*i+3, 1)
  }
  ITER8(31, 32, 33, 0)

  const int hrow0 = rowbase + mt*BM + wm*128;
#pragma unroll
  for (int m = 0; m < 8; ++m){
    int row = hrow0 + m*16 + l15;
#pragma unroll
    for (int nf = 0; nf < 2; ++nf){
      f16x4 hv;
#pragma unroll
      for (int j = 0; j < 4; ++j){
        float gv = acc[m][nf][j], uv = acc[m][nf+2][j];
        hv[j] = (_Float16)(gv / (1.f + __expf(-gv)) * uv);
      }
      *(f16x4*)(H + (size_t)row * FFN + n0 + wn*32 + nf*16 + hi*4) = hv;
    }
  }
}

// ================= grouped GEMM 2: Y = H @ Wd (plain stores, split Y) =================
__global__ __launch_bounds__(512, 2) void k_down(
    const _Float16* __restrict__ H,
    const _Float16* __restrict__ wdT,   // [E][D][F]
    const int* __restrict__ counts,
    _Float16* __restrict__ Yw2,         // rows < 32768  (dead wuT region)
    _Float16* __restrict__ Yxh)         // rows >= 32768 (dead xh region)
{
  __shared__ __align__(128) char smem[131072];
  char* ldsA = smem;
  char* ldsB = smem + 65536;

  // r6 mapping: XCD chunking + 4-N-column grouping (grid = MAXT*8)
  const int bid = blockIdx.x;
  const int vid = (bid & 7) * MAXT + (bid >> 3);
  const int g = vid / (4*MAXT), rem = vid % (4*MAXT);
  const int mt_lin = rem >> 2;
  const int n0 = (g*4 + (rem & 3)) * 256;

  int e = -1, mt = 0, rowbase = 0;
  { int at = 0, rb = 0;
    for (int i = 0; i < NEXP; ++i){
      int c = counts[i]; int nt = (c + 255) >> 8;
      if (e < 0 && mt_lin < at + nt){ e = i; mt = mt_lin - at; rowbase = rb; }
      at += nt; rb += nt * BM;
    } }
  if (e < 0) return;

  const int tid = threadIdx.x, lane = tid & 63, w = tid >> 6;
  const int wm = w >> 2, wn = w & 3, hi = lane >> 4, l15 = lane & 15;
  const int wdst = w * 1024;

  const int chunk = (((tid & 7) ^ ((tid >> 3) & 7)) << 4);
  const char* srcA[2][2]; const char* srcB[2][2];
#pragma unroll
  for (int h = 0; h < 2; ++h)
#pragma unroll
    for (int j = 0; j < 2; ++j){
      int r = h*128 + j*64 + (tid >> 3);
      srcA[h][j] = (const char*)(H + (size_t)(rowbase + mt*BM + r) * FFN) + chunk;
      srcB[h][j] = (const char*)(wdT + ((size_t)e * DMODEL + n0 + r) * (size_t)FFN) + chunk;
    }

  const char* Ab = ldsA + wm*16384;
  const char* Bb = ldsB + (wn >> 1)*16384 + (wn & 1)*8192;
  const int sl0 = (hi ^ (l15 & 7)) << 4;
  int aB[8], bB[4];
#pragma unroll
  for (int m = 0; m < 8; ++m) aB[m] = m*2048 + l15*128 + sl0;
#pragma unroll
  for (int n = 0; n < 4; ++n) bB[n] = n*2048 + l15*128 + sl0;

  f32x4 acc[8][4];
#pragma unroll
  for (int m = 0; m < 8; ++m)
#pragma unroll
    for (int n = 0; n < 4; ++n) acc[m][n] = (f32x4)(0.0f);

  STG_B(0,0); STG_B(0,1); STG_A(0,0); STG_A(0,1); STG_B(1,0);
  VMW2; BAR;

  f16x8 af[4], bf[4];
  for (int i = 0; i < NIT-1; ++i){
    ITER8(2*i+1, 2*i+2, 2*i+3, 1)
  }
  ITER8(31, 32, 33, 0)

  const int row0 = rowbase + mt*BM + wm*128;
#pragma unroll
  for (int m = 0; m < 8; ++m){
    int row = row0 + m*16 + l15;
    _Float16* yb = (row < 32768) ? (Yw2 + (size_t)row * DMODEL)
                                 : (Yxh + (size_t)(row - 32768) * DMODEL);
#pragma unroll
    for (int n = 0; n < 4; ++n){
      f16x4 yv;
#pragma unroll
      for (int j = 0; j < 4; ++j) yv[j] = (_Float16)acc[m][n][j];
      *(f16x4*)(yb + n0 + wn*64 + n*16 + hi*4) = yv;
    }
  }
}

// ---------------- combine: out[t] = sum_k wk * Y[slot_k] ----------------
__global__ __launch_bounds__(256) void k_combine(const _Float16* __restrict__ Yw2,
                                                 const _Float16* __restrict__ Yxh,
                                                 const int* __restrict__ counts,
                                                 const int* __restrict__ slotmap,
                                                 const float* __restrict__ wk,
                                                 float* __restrict__ out){
  __shared__ int pre[NEXP];
  const int t = blockIdx.x, c = threadIdx.x;
  if (c == 0){
    int a = 0;
    for (int i = 0; i < NEXP; ++i){ pre[i] = a; a += ((counts[i] + 255) >> 8) << 8; }
  }
  __syncthreads();
  float o[8];
#pragma unroll
  for (int i = 0; i < 8; ++i) o[i] = 0.f;
#pragma unroll
  for (int k = 0; k < TOPK; ++k){
    int sm = slotmap[t*TOPK + k];
    int row = pre[sm >> 16] + (sm & 0xffff);
    float wv = wk[t*TOPK + k];
    const _Float16* yb = (row < 32768) ? (Yw2 + (size_t)row * DMODEL)
                                       : (Yxh + (size_t)(row - 32768) * DMODEL);
    f16x8 y = *(const f16x8*)(yb + c*8);
#pragma unroll
    for (int i = 0; i < 8; ++i) o[i] += wv * (float)y[i];
  }
  float4 lo = {o[0], o[1], o[2], o[3]}, hu = {o[4], o[5], o[6], o[7]};
  float* op = out + (size_t)t * DMODEL + c*8;
  *(float4*)op = lo;
  *(float4*)(op + 4) = hu;
}

// ---------------- host launch ----------------
extern "C" void kernel_launch(void* const* d_in, const int* in_sizes, int n_in,
                              void* d_out, int out_size, void* d_ws, size_t ws_size,
                              hipStream_t stream)
{
  const float* x  = (const float*)d_in[0];
  const float* wr = (const float*)d_in[1];
  const float* wg = (const float*)d_in[2];
  const float* wu = (const float*)d_in[3];
  const float* wd = (const float*)d_in[4];
  float* out = (float*)d_out;
  char* ws = (char*)d_ws;

  // layout (NEED ~588 MB <= proven-available 605 MB):
  // [counts | ids | slotmap | wk | xh(32M) | W1(134M) | H(151M) | W2(134M) | WD(134M)]
  const size_t OFF_IDS  = 256;
  const size_t OFF_SLOT = OFF_IDS  + (size_t)NEXP*STRIDE*4;
  const size_t OFF_WK   = OFF_SLOT + (size_t)NTOK*TOPK*4;
  const size_t OFF_XH   = OFF_WK   + (size_t)NTOK*TOPK*4;
  const size_t OFF_W1   = OFF_XH   + (size_t)NTOK*DMODEL*2;
  const size_t OFF_H    = OFF_W1   + (size_t)NEXP*DMODEL*FFN*2;
  const size_t OFF_W2   = OFF_H    + (size_t)MAXT*BM*FFN*2;
  const size_t OFF_WD   = OFF_W2   + (size_t)NEXP*DMODEL*FFN*2;
  const size_t NEED     = OFF_WD   + (size_t)NEXP*DMODEL*FFN*2;
  if (ws_size < NEED){ k_sentinel<<<1,1,0,stream>>>(out); return; }

  int*      counts  = (int*)ws;
  int*      ids     = (int*)(ws + OFF_IDS);
  int*      slotmap = (int*)(ws + OFF_SLOT);
  float*    wk      = (float*)(ws + OFF_WK);
  _Float16* xh      = (_Float16*)(ws + OFF_XH);
  _Float16* wgT     = (_Float16*)(ws + OFF_W1);
  _Float16* wuT     = (_Float16*)(ws + OFF_W2);
  _Float16* wdT     = (_Float16*)(ws + OFF_WD);
  _Float16* H       = (_Float16*)(ws + OFF_H);
  _Float16* Yw2     = (_Float16*)(ws + OFF_W2);   // alias wuT (dead after gateup)
  _Float16* Yxh     = (_Float16*)(ws + OFF_XH);   // alias xh  (dead after gateup)

  hipMemsetAsync(ws, 0, OFF_SLOT, stream);    // counts + ids

  k_router<<<NTOK/RTB, 256, 0, stream>>>(x, wr, counts, ids, slotmap, wk, xh);
  k_transpose3<<<dim3(32,32,48), 256, 0, stream>>>(wg, wu, wd, wgT, wuT, wdT);
  k_gateup<<<MAXT*16, 512, 0, stream>>>(xh, wgT, wuT, counts, ids, H);
  k_down<<<MAXT*8, 512, 0, stream>>>(H, wdT, counts, Yw2, Yxh);
  k_combine<<<NTOK, 256, 0, stream>>>(Yw2, Yxh, counts, slotmap, wk, out);
}